// Round 1
// baseline (294.885 us; speedup 1.0000x reference)
//
#include <hip/hip_runtime.h>
#include <hip/hip_bf16.h>

// Problem constants
#define N_ROWS 8192
#define D_DIM  1024
#define HALF_N 4096
constexpr float INV_T = 1.0f / 0.07f;   // 14.2857143 — also the fixed softmax max M

typedef __attribute__((ext_vector_type(8))) short short8;  // 8 bf16 (4 VGPRs)
typedef __attribute__((ext_vector_type(4))) float f32x4;

__device__ __forceinline__ unsigned short f2bf(float x) {
    __hip_bfloat16 h = __float2bfloat16(x);
    return *reinterpret_cast<unsigned short*>(&h);
}

// async global->LDS, 16B/lane. LDS dest is wave-uniform base + lane*16.
__device__ __forceinline__ void async_ld16(const void* g, void* lds) {
    __builtin_amdgcn_global_load_lds(
        (const __attribute__((address_space(1))) void*)g,
        (__attribute__((address_space(3))) void*)lds,
        16, 0, 0);
}

// ---------------------------------------------------------------------------
// Kernel 1: row norms + bf16 normalized copy.  One wave per row.
__global__ __launch_bounds__(256) void norm_kernel(const float* __restrict__ feat,
                                                   unsigned short* __restrict__ fn,
                                                   float* __restrict__ norms) {
    const int w = threadIdx.x >> 6, lane = threadIdx.x & 63;
    const int row = blockIdx.x * 4 + w;
    const float4* src = (const float4*)(feat + (size_t)row * D_DIM);
    float4 v[4];
    float ss = 0.f;
#pragma unroll
    for (int t = 0; t < 4; ++t) {
        v[t] = src[lane + 64 * t];
        ss += v[t].x * v[t].x + v[t].y * v[t].y + v[t].z * v[t].z + v[t].w * v[t].w;
    }
#pragma unroll
    for (int off = 32; off; off >>= 1) ss += __shfl_xor(ss, off);
    float nrm = fmaxf(sqrtf(ss), 1e-8f);
    if (lane == 0) norms[row] = nrm;
    const float inv = 1.0f / nrm;
    ushort4* dst = (ushort4*)(fn + (size_t)row * D_DIM);
#pragma unroll
    for (int t = 0; t < 4; ++t) {
        ushort4 o;
        o.x = f2bf(v[t].x * inv);
        o.y = f2bf(v[t].y * inv);
        o.z = f2bf(v[t].z * inv);
        o.w = f2bf(v[t].w * inv);
        dst[lane + 64 * t] = o;
    }
}

// ---------------------------------------------------------------------------
// Kernel 2: s_target[i] = (f_i . f_{(i+B) mod N}) / (|f_i||f_pair|) / T, fp32 exact.
__global__ __launch_bounds__(256) void target_kernel(const float* __restrict__ feat,
                                                     const float* __restrict__ norms,
                                                     float* __restrict__ s_target) {
    const int w = threadIdx.x >> 6, lane = threadIdx.x & 63;
    const int row = blockIdx.x * 4 + w;
    const int pair = (row + HALF_N) & (N_ROWS - 1);
    const float4* a = (const float4*)(feat + (size_t)row * D_DIM);
    const float4* b = (const float4*)(feat + (size_t)pair * D_DIM);
    float d = 0.f;
#pragma unroll
    for (int t = 0; t < 4; ++t) {
        float4 x = a[lane + 64 * t], y = b[lane + 64 * t];
        d += x.x * y.x + x.y * y.y + x.z * y.z + x.w * y.w;
    }
#pragma unroll
    for (int off = 32; off; off >>= 1) d += __shfl_xor(d, off);
    if (lane == 0) s_target[row] = d / (norms[row] * norms[pair]) * INV_T;
}

// ---------------------------------------------------------------------------
// Kernel 3: flash-style sim GEMM (NT, A=B=fn) + fixed-max exp accumulation.
// Block: 256 thr (4 waves). Row tile 128 (blockIdx.y), col group 512 = 4 x 128
// col tiles (blockIdx.x). m97 structure: BK=32, global_load_lds x16B,
// ds_read_b128 frags, 16x16x32 bf16 MFMA, 4x4 subtiles per wave.
__global__ __launch_bounds__(256) void simgemm_kernel(const unsigned short* __restrict__ fn,
                                                      float* __restrict__ row_sum) {
    __shared__ __align__(16) unsigned short As[128 * 32];
    __shared__ __align__(16) unsigned short Bs[128 * 32];
    const int tid = threadIdx.x;
    const int w = tid >> 6, lane = tid & 63;
    const int q = lane >> 4, c16 = lane & 15;
    const int r0 = blockIdx.y * 128;
    const int cg0 = blockIdx.x * 512;
    const int wr = (w >> 1) * 64;  // wave's row base within tile
    const int wc = (w & 1) * 64;   // wave's col base within tile
    // staging geometry: chunk = 16 rows x 32 k (1024 B); wave w stages chunks 2w, 2w+1
    const int ch0 = w * 2;
    const int srow = lane >> 2;          // row within chunk
    const int skoff = (lane & 3) * 8;    // k element offset

    float rs[4][4];                      // per-(row-subtile, reg) partial exp-sums
#pragma unroll
    for (int i = 0; i < 4; ++i)
#pragma unroll
        for (int r = 0; r < 4; ++r) rs[i][r] = 0.f;

    for (int ct = 0; ct < 4; ++ct) {
        const int c0 = cg0 + ct * 128;
        f32x4 acc[4][4];
#pragma unroll
        for (int i = 0; i < 4; ++i)
#pragma unroll
            for (int j = 0; j < 4; ++j) acc[i][j] = (f32x4){0.f, 0.f, 0.f, 0.f};

        for (int kt = 0; kt < 32; ++kt) {
            const int k0 = kt * 32;
            __syncthreads();  // previous tile's reads done before overwrite
#pragma unroll
            for (int cc = 0; cc < 2; ++cc) {
                const int ch = ch0 + cc;
                const size_t arow = (size_t)(r0 + ch * 16 + srow);
                async_ld16(fn + arow * D_DIM + k0 + skoff, (void*)&As[ch * 512]);
                const size_t brow = (size_t)(c0 + ch * 16 + srow);
                async_ld16(fn + brow * D_DIM + k0 + skoff, (void*)&Bs[ch * 512]);
            }
            __syncthreads();  // drains vmcnt(0): staging visible

            short8 af[4], bf[4];
#pragma unroll
            for (int i = 0; i < 4; ++i)
                af[i] = *(const short8*)&As[(wr + i * 16 + c16) * 32 + q * 8];
#pragma unroll
            for (int j = 0; j < 4; ++j)
                bf[j] = *(const short8*)&Bs[(wc + j * 16 + c16) * 32 + q * 8];
#pragma unroll
            for (int i = 0; i < 4; ++i)
#pragma unroll
                for (int j = 0; j < 4; ++j)
                    acc[i][j] = __builtin_amdgcn_mfma_f32_16x16x32_bf16(af[i], bf[j], acc[i][j], 0, 0, 0);
        }

        // epilogue: exp(sim - M), diag masked, accumulate per-row
#pragma unroll
        for (int i = 0; i < 4; ++i) {
            const int growb = r0 + wr + i * 16 + q * 4;
#pragma unroll
            for (int r = 0; r < 4; ++r) {
                float s = 0.f;
#pragma unroll
                for (int j = 0; j < 4; ++j) {
                    const int gcol = c0 + wc + j * 16 + c16;
                    float sim = acc[i][j][r] * INV_T;
                    float e = __expf(sim - INV_T);
                    if (growb + r == gcol) e = 0.f;  // diagonal mask
                    s += e;
                }
                rs[i][r] += s;
            }
        }
    }

    // reduce across the 16 col-lanes of each quad, one atomic per row
#pragma unroll
    for (int i = 0; i < 4; ++i)
#pragma unroll
        for (int r = 0; r < 4; ++r) {
            float s = rs[i][r];
            s += __shfl_xor(s, 1);
            s += __shfl_xor(s, 2);
            s += __shfl_xor(s, 4);
            s += __shfl_xor(s, 8);
            if (c16 == 0) atomicAdd(&row_sum[r0 + wr + i * 16 + q * 4 + r], s);
        }
}

// ---------------------------------------------------------------------------
// Kernel 4: loss = mean_i [ M + log(row_sum_i) - s_target_i ]
__global__ __launch_bounds__(256) void loss_kernel(const float* __restrict__ row_sum,
                                                   const float* __restrict__ s_target,
                                                   float* __restrict__ out) {
    float local = 0.f;
    for (int i = threadIdx.x; i < N_ROWS; i += 256)
        local += (INV_T + __logf(row_sum[i])) - s_target[i];
#pragma unroll
    for (int off = 32; off; off >>= 1) local += __shfl_xor(local, off);
    __shared__ float part[4];
    if ((threadIdx.x & 63) == 0) part[threadIdx.x >> 6] = local;
    __syncthreads();
    if (threadIdx.x == 0)
        out[0] = (part[0] + part[1] + part[2] + part[3]) * (1.0f / N_ROWS);
}

// ---------------------------------------------------------------------------
extern "C" void kernel_launch(void* const* d_in, const int* in_sizes, int n_in,
                              void* d_out, int out_size, void* d_ws, size_t ws_size,
                              hipStream_t stream) {
    const float* feat = (const float*)d_in[0];
    float* out = (float*)d_out;
    char* ws = (char*)d_ws;

    unsigned short* fn = (unsigned short*)ws;                 // 8192*1024 bf16 = 16 MiB
    size_t off = (size_t)N_ROWS * D_DIM * sizeof(unsigned short);
    float* norms = (float*)(ws + off);    off += N_ROWS * sizeof(float);
    float* row_sum = (float*)(ws + off);  off += N_ROWS * sizeof(float);
    float* s_target = (float*)(ws + off);

    hipMemsetAsync(row_sum, 0, N_ROWS * sizeof(float), stream);
    norm_kernel<<<N_ROWS / 4, 256, 0, stream>>>(feat, fn, norms);
    target_kernel<<<N_ROWS / 4, 256, 0, stream>>>(feat, norms, s_target);
    simgemm_kernel<<<dim3(16, 64), 256, 0, stream>>>(fn, row_sum);
    loss_kernel<<<1, 256, 0, stream>>>(row_sum, s_target, out);
}